// Round 3
// baseline (414.770 us; speedup 1.0000x reference)
//
#include <hip/hip_runtime.h>
#include <hip/hip_bf16.h>
#include <cstdint>
#include <cstddef>

#define B_     2
#define E_     196608
#define XD_    128
#define NREC_  12288
#define EOUT_  128
#define LIN_   256
#define LOUT_  256
#define M_     (B_ * NREC_)   // 24576 FFN rows

typedef __attribute__((ext_vector_type(8))) short short8;
typedef __attribute__((ext_vector_type(4))) float f32x4;

__device__ __forceinline__ unsigned short f2bf(float f) {
    union { float f; unsigned u; } v; v.f = f;
    unsigned r = v.u + 0x7FFFu + ((v.u >> 16) & 1u);
    return (unsigned short)(r >> 16);
}

// ---- precompute combined FFN weights ----
// L1T[n][k] (bf16, k-major rows for MFMA B-frags):
//   k <  128 : M1[k][n] = sum_c W2[k][c] * L1[c][n]   (W2 folded into L1 top)
//   k >= 128 : L1[k][n]                                (x part unchanged)
// L2T[n][k] = L2[k][n]
// v[n] = sum_c b2[c] * L1[c][n]   (scaled by per-row edge count in ffn)
__global__ __launch_bounds__(256) void precompute(
        const float* __restrict__ W2, const float* __restrict__ b2,
        const float* __restrict__ L1, const float* __restrict__ L2,
        unsigned short* __restrict__ L1T, unsigned short* __restrict__ L2T,
        float* __restrict__ v) {
    int bid = blockIdx.x;
    int n = threadIdx.x;    // 0..255
    if (bid < 128) {
        int j = bid;
        float a0 = 0.f, a1 = 0.f, a2 = 0.f, a3 = 0.f;
        for (int c = 0; c < 128; c += 4) {
            a0 = fmaf(W2[j * 128 + c + 0], L1[(c + 0) * 256 + n], a0);
            a1 = fmaf(W2[j * 128 + c + 1], L1[(c + 1) * 256 + n], a1);
            a2 = fmaf(W2[j * 128 + c + 2], L1[(c + 2) * 256 + n], a2);
            a3 = fmaf(W2[j * 128 + c + 3], L1[(c + 3) * 256 + n], a3);
        }
        L1T[n * 256 + j] = f2bf((a0 + a1) + (a2 + a3));
        if (j == 0) {
            float s0 = 0.f, s1 = 0.f;
            for (int c = 0; c < 128; c += 2) {
                s0 = fmaf(b2[c + 0], L1[(c + 0) * 256 + n], s0);
                s1 = fmaf(b2[c + 1], L1[(c + 1) * 256 + n], s1);
            }
            v[n] = s0 + s1;
        }
    } else if (bid < 256) {
        int k = bid;                          // 128..255
        L1T[n * 256 + k] = f2bf(L1[k * 256 + n]);
    } else {
        int k = bid - 256;                    // 0..255
        L2T[n * 256 + k] = f2bf(L2[k * 256 + n]);
    }
}

// ---- histogram of receivers ----
__global__ __launch_bounds__(256) void count_kernel(const int* __restrict__ recv,
                                                    int* __restrict__ cnt) {
    int e = blockIdx.x * 256 + threadIdx.x;
    if (e < E_) atomicAdd(&cnt[recv[e]], 1);
}

// ---- exclusive scan over 12288 counts (single block, 1024 thr x 12 items) ----
__global__ __launch_bounds__(1024) void scan_kernel(const int* __restrict__ cnt,
                                                    int* __restrict__ rowStart,
                                                    int* __restrict__ cursor) {
    __shared__ int sums[1024];
    int tid = threadIdx.x;
    int base = tid * 12;
    int local[12];
    int s = 0;
    #pragma unroll
    for (int j = 0; j < 12; ++j) { local[j] = s; s += cnt[base + j]; }
    sums[tid] = s;
    __syncthreads();
    for (int off = 1; off < 1024; off <<= 1) {
        int vv = sums[tid];
        int add = (tid >= off) ? sums[tid - off] : 0;
        __syncthreads();
        sums[tid] = vv + add;
        __syncthreads();
    }
    int excl = (tid == 0) ? 0 : sums[tid - 1];
    #pragma unroll
    for (int j = 0; j < 12; ++j) {
        int vv = excl + local[j];
        rowStart[base + j] = vv;
        cursor[base + j] = vv;
    }
    if (tid == 1023) rowStart[NREC_] = excl + s;   // == E_
}

// ---- fill CSR edge id lists ----
__global__ __launch_bounds__(256) void fill_kernel(const int* __restrict__ recv,
                                                   int* __restrict__ cursor,
                                                   int* __restrict__ edge_ids) {
    int e = blockIdx.x * 256 + threadIdx.x;
    if (e < E_) {
        int p = atomicAdd(&cursor[recv[e]], 1);
        edge_ids[p] = e;
    }
}

// ---- fused gather v3: 16 edges/iter, dwordx4 x-loads held in flight ----
// Thread roles (128 threads):
//   S-part: col c = t (0..127), accumulates silu(ea@W1+b1)[c] over ALL edges.
//   X-part: p = t>>6 (edge parity), s = t&63, b = s>>5 (batch), c4 = s&31;
//           accumulates float4 x[b][e][4*c4..] over edges of parity p.
// agg layout: [B][NREC][256]; cols 0..127 = S (dup), 128..255 = x sum.
__global__ __launch_bounds__(128) void gather_kernel(
        const float* __restrict__ x, const float* __restrict__ ea,
        const float* __restrict__ W1, const float* __restrict__ b1,
        const int* __restrict__ rowStart, const int* __restrict__ edge_ids,
        unsigned short* __restrict__ agg_bf) {
    __shared__ f32x4 xred[128];
    int r = blockIdx.x;
    int t = threadIdx.x;            // 0..127
    int k0 = __builtin_amdgcn_readfirstlane(rowStart[r]);
    int k1 = __builtin_amdgcn_readfirstlane(rowStart[r + 1]);

    float w10 = W1[t], w11 = W1[128 + t], w12 = W1[256 + t], w13 = W1[384 + t];
    float bb1 = b1[t];
    float accS = 0.f;

    int p  = t >> 6;
    int s  = t & 63;
    int b  = s >> 5;
    int c4 = s & 31;
    const float* xbase = x + (size_t)b * E_ * 128 + c4 * 4;
    f32x4 aX = {0.f, 0.f, 0.f, 0.f};

    for (int k = k0; k < k1; k += 16) {
        int ecnt = k1 - k;          // >= 1
        int eid[16];
        #pragma unroll
        for (int u = 0; u < 16; ++u) {
            int idx = k + u;
            idx = (idx < k1) ? idx : (k1 - 1);
            eid[u] = __builtin_amdgcn_readfirstlane(edge_ids[idx]);
        }
        // issue all 8 x dwordx4 loads (2 edges per instruction), keep in flight
        f32x4 xv[8];
        #pragma unroll
        for (int i = 0; i < 8; ++i)
            xv[i] = *(const f32x4*)(xbase + (size_t)eid[2 * i + p] * 128);
        // MLP on ea (uniform scalar loads) while x loads are in flight
        #pragma unroll
        for (int u = 0; u < 16; ++u) {
            float4 q = *(const float4*)(ea + (size_t)eid[u] * 4);
            float pr = fmaf(q.x, w10, fmaf(q.y, w11,
                       fmaf(q.z, w12, fmaf(q.w, w13, bb1))));
            float sv = pr / (1.f + __expf(-pr));
            accS += (u < ecnt) ? sv : 0.f;
        }
        // consume x loads with tail mask
        #pragma unroll
        for (int i = 0; i < 8; ++i) {
            float m = ((2 * i + p) < ecnt) ? 1.f : 0.f;
            aX[0] = fmaf(m, xv[i][0], aX[0]);
            aX[1] = fmaf(m, xv[i][1], aX[1]);
            aX[2] = fmaf(m, xv[i][2], aX[2]);
            aX[3] = fmaf(m, xv[i][3], aX[3]);
        }
    }

    xred[t] = aX;
    unsigned short sb = f2bf(accS);
    agg_bf[(size_t)r * 256 + t] = sb;
    agg_bf[(size_t)(NREC_ + r) * 256 + t] = sb;
    __syncthreads();
    if (t < 64) {
        f32x4 v0 = xred[t];
        f32x4 v1 = xred[t + 64];
        float t0 = v0[0] + v1[0], t1 = v0[1] + v1[1];
        float t2 = v0[2] + v1[2], t3 = v0[3] + v1[3];
        unsigned lo = (unsigned)f2bf(t0) | ((unsigned)f2bf(t1) << 16);
        unsigned hi = (unsigned)f2bf(t2) | ((unsigned)f2bf(t3) << 16);
        uint2 pk = make_uint2(lo, hi);
        // slot: batch b, float4-col c4  (recompute from t<64 view)
        int bb = t >> 5, cc = t & 31;
        *(uint2*)(agg_bf + ((size_t)(bb * NREC_ + r) * 256 + 128 + cc * 4)) = pk;
    }
}

// ---- output FFN: out = silu(agg @ L1comb + c1 + cnt*v) @ L2 + c2 ----
// bf16 MFMA 16x16x32. Each block: 64 rows (4 waves x 16 rows).
__global__ __launch_bounds__(256) void ffn_kernel(
        const unsigned short* __restrict__ agg,
        const unsigned short* __restrict__ L1T, const float* __restrict__ c1,
        const unsigned short* __restrict__ L2T, const float* __restrict__ c2,
        const float* __restrict__ v, const int* __restrict__ cnt,
        float* __restrict__ out) {
    __shared__ unsigned short T[64][264];
    int tid  = threadIdx.x;
    int wave = tid >> 6;
    int lane = tid & 63;
    int quad = lane >> 4;
    int l16  = lane & 15;
    int m0 = blockIdx.x * 64 + wave * 16;

    float cntv[4];
    #pragma unroll
    for (int rr = 0; rr < 4; ++rr) {
        int m = m0 + quad * 4 + rr;
        int r = (m >= NREC_) ? m - NREC_ : m;
        cntv[rr] = (float)cnt[r];
    }

    short8 afrag[8];
    const unsigned short* aptr = agg + (size_t)(m0 + l16) * 256 + quad * 8;
    #pragma unroll
    for (int ks = 0; ks < 8; ++ks)
        afrag[ks] = *(const short8*)(aptr + ks * 32);

    #pragma unroll 2
    for (int nt = 0; nt < 16; ++nt) {
        f32x4 acc = {0.f, 0.f, 0.f, 0.f};
        const unsigned short* bptr = L1T + (size_t)(nt * 16 + l16) * 256 + quad * 8;
        #pragma unroll
        for (int ks = 0; ks < 8; ++ks) {
            short8 bfrag = *(const short8*)(bptr + ks * 32);
            acc = __builtin_amdgcn_mfma_f32_16x16x32_bf16(afrag[ks], bfrag, acc, 0, 0, 0);
        }
        #pragma unroll
        for (int rr = 0; rr < 4; ++rr) {
            int row = quad * 4 + rr;
            int col = nt * 16 + l16;
            float pv = acc[rr] + c1[col] + cntv[rr] * v[col];
            pv = pv / (1.f + __expf(-pv));
            T[wave * 16 + row][col] = f2bf(pv);
        }
    }
    __syncthreads();

    short8 afrag2[8];
    #pragma unroll
    for (int ks = 0; ks < 8; ++ks)
        afrag2[ks] = *(const short8*)&T[wave * 16 + l16][ks * 32 + quad * 8];

    #pragma unroll 2
    for (int nt = 0; nt < 16; ++nt) {
        f32x4 acc = {0.f, 0.f, 0.f, 0.f};
        const unsigned short* bptr = L2T + (size_t)(nt * 16 + l16) * 256 + quad * 8;
        #pragma unroll
        for (int ks = 0; ks < 8; ++ks) {
            short8 bfrag = *(const short8*)(bptr + ks * 32);
            acc = __builtin_amdgcn_mfma_f32_16x16x32_bf16(afrag2[ks], bfrag, acc, 0, 0, 0);
        }
        #pragma unroll
        for (int rr = 0; rr < 4; ++rr) {
            int row = m0 + quad * 4 + rr;
            int col = nt * 16 + l16;
            out[(size_t)row * 256 + col] = acc[rr] + c2[col];
        }
    }
}

extern "C" void kernel_launch(void* const* d_in, const int* in_sizes, int n_in,
                              void* d_out, int out_size, void* d_ws, size_t ws_size,
                              hipStream_t stream) {
    const float* x          = (const float*)d_in[0];
    const float* edge_attr  = (const float*)d_in[1];
    const int*   edge_index = (const int*)d_in[2];
    const float* W1 = (const float*)d_in[3];
    const float* b1 = (const float*)d_in[4];
    const float* W2 = (const float*)d_in[5];
    const float* b2 = (const float*)d_in[6];
    const float* L1 = (const float*)d_in[7];
    const float* c1 = (const float*)d_in[8];
    const float* L2 = (const float*)d_in[9];
    const float* c2 = (const float*)d_in[10];
    float* out = (float*)d_out;

    // workspace layout (16B aligned)
    int* cnt      = (int*)d_ws;                 // 12288
    int* rowStart = cnt + NREC_;                // 12289 (pad to 12292)
    int* cursor   = rowStart + NREC_ + 4;       // 12288
    int* edge_ids = cursor + NREC_;             // 196608
    unsigned short* agg_bf = (unsigned short*)(edge_ids + E_);   // M_*256
    unsigned short* L1T = agg_bf + (size_t)M_ * 256;             // 65536
    unsigned short* L2T = L1T + 256 * 256;                       // 65536
    float* v = (float*)(L2T + 256 * 256);                        // 256

    const int* recv = edge_index + E_;   // edge_index[1]

    hipMemsetAsync(cnt, 0, NREC_ * sizeof(int), stream);
    precompute<<<512, 256, 0, stream>>>(W2, b2, L1, L2, L1T, L2T, v);
    count_kernel<<<(E_ + 255) / 256, 256, 0, stream>>>(recv, cnt);
    scan_kernel<<<1, 1024, 0, stream>>>(cnt, rowStart, cursor);
    fill_kernel<<<(E_ + 255) / 256, 256, 0, stream>>>(recv, cursor, edge_ids);
    gather_kernel<<<NREC_, 128, 0, stream>>>(x, edge_attr, W1, b1,
                                             rowStart, edge_ids, agg_bf);
    ffn_kernel<<<M_ / 64, 256, 0, stream>>>(agg_bf, L1T, c1, L2T, c2, v, cnt, out);
}

// Round 4
// 412.471 us; speedup vs baseline: 1.0056x; 1.0056x over previous
//
#include <hip/hip_runtime.h>
#include <hip/hip_bf16.h>
#include <cstdint>
#include <cstddef>

#define B_     2
#define E_     196608
#define XD_    128
#define NREC_  12288
#define EOUT_  128
#define LIN_   256
#define LOUT_  256
#define M_     (B_ * NREC_)   // 24576 FFN rows

typedef __attribute__((ext_vector_type(8))) short short8;
typedef __attribute__((ext_vector_type(4))) float f32x4;

__device__ __forceinline__ unsigned short f2bf(float f) {
    union { float f; unsigned u; } v; v.f = f;
    unsigned r = v.u + 0x7FFFu + ((v.u >> 16) & 1u);
    return (unsigned short)(r >> 16);
}

// ---- precompute combined FFN weights ----
// L1T[n][k] (bf16, k-major rows for MFMA B-frags):
//   k <  128 : M1[k][n] = sum_c W2[k][c] * L1[c][n]   (W2 folded into L1 top)
//   k >= 128 : L1[k][n]                                (x part unchanged)
// L2T[n][k] = L2[k][n]
// v[n] = sum_c b2[c] * L1[c][n]   (scaled by per-row edge count in ffn)
__global__ __launch_bounds__(256) void precompute(
        const float* __restrict__ W2, const float* __restrict__ b2,
        const float* __restrict__ L1, const float* __restrict__ L2,
        unsigned short* __restrict__ L1T, unsigned short* __restrict__ L2T,
        float* __restrict__ v) {
    int bid = blockIdx.x;
    int n = threadIdx.x;    // 0..255
    if (bid < 128) {
        int j = bid;
        float a0 = 0.f, a1 = 0.f, a2 = 0.f, a3 = 0.f;
        for (int c = 0; c < 128; c += 4) {
            a0 = fmaf(W2[j * 128 + c + 0], L1[(c + 0) * 256 + n], a0);
            a1 = fmaf(W2[j * 128 + c + 1], L1[(c + 1) * 256 + n], a1);
            a2 = fmaf(W2[j * 128 + c + 2], L1[(c + 2) * 256 + n], a2);
            a3 = fmaf(W2[j * 128 + c + 3], L1[(c + 3) * 256 + n], a3);
        }
        L1T[n * 256 + j] = f2bf((a0 + a1) + (a2 + a3));
        if (j == 0) {
            float s0 = 0.f, s1 = 0.f;
            for (int c = 0; c < 128; c += 2) {
                s0 = fmaf(b2[c + 0], L1[(c + 0) * 256 + n], s0);
                s1 = fmaf(b2[c + 1], L1[(c + 1) * 256 + n], s1);
            }
            v[n] = s0 + s1;
        }
    } else if (bid < 256) {
        int k = bid;                          // 128..255
        L1T[n * 256 + k] = f2bf(L1[k * 256 + n]);
    } else {
        int k = bid - 256;                    // 0..255
        L2T[n * 256 + k] = f2bf(L2[k * 256 + n]);
    }
}

// ---- histogram of receivers ----
__global__ __launch_bounds__(256) void count_kernel(const int* __restrict__ recv,
                                                    int* __restrict__ cnt) {
    int e = blockIdx.x * 256 + threadIdx.x;
    if (e < E_) atomicAdd(&cnt[recv[e]], 1);
}

// ---- exclusive scan over 12288 counts (single block, 1024 thr x 12 items) ----
__global__ __launch_bounds__(1024) void scan_kernel(const int* __restrict__ cnt,
                                                    int* __restrict__ rowStart,
                                                    int* __restrict__ cursor) {
    __shared__ int sums[1024];
    int tid = threadIdx.x;
    int base = tid * 12;
    int local[12];
    int s = 0;
    #pragma unroll
    for (int j = 0; j < 12; ++j) { local[j] = s; s += cnt[base + j]; }
    sums[tid] = s;
    __syncthreads();
    for (int off = 1; off < 1024; off <<= 1) {
        int vv = sums[tid];
        int add = (tid >= off) ? sums[tid - off] : 0;
        __syncthreads();
        sums[tid] = vv + add;
        __syncthreads();
    }
    int excl = (tid == 0) ? 0 : sums[tid - 1];
    #pragma unroll
    for (int j = 0; j < 12; ++j) {
        int vv = excl + local[j];
        rowStart[base + j] = vv;
        cursor[base + j] = vv;
    }
    if (tid == 1023) rowStart[NREC_] = excl + s;   // == E_
}

// ---- fill CSR edge id lists ----
__global__ __launch_bounds__(256) void fill_kernel(const int* __restrict__ recv,
                                                   int* __restrict__ cursor,
                                                   int* __restrict__ edge_ids) {
    int e = blockIdx.x * 256 + threadIdx.x;
    if (e < E_) {
        int p = atomicAdd(&cursor[recv[e]], 1);
        edge_ids[p] = e;
    }
}

// ---- fused gather v4: one WAVE per receiver, 8 edges in flight, no LDS ----
// Wave lanes: b = lane>>5 (batch), c4 = lane&31 (float4 col) -> one dwordx4
// per lane covers the full 1KB (2 batches x 512B) of one edge.
// S-part: lane computes MLP cols (lane) and (lane+64) from uniform ea loads.
// agg layout: [B][NREC][256]; cols 0..127 = S (dup per batch), 128..255 = x.
__global__ __launch_bounds__(256) void gather_kernel(
        const float* __restrict__ x, const float* __restrict__ ea,
        const float* __restrict__ W1, const float* __restrict__ b1,
        const int* __restrict__ rowStart, const int* __restrict__ edge_ids,
        unsigned short* __restrict__ agg_bf) {
    int wave = threadIdx.x >> 6;
    int lane = threadIdx.x & 63;
    int r = blockIdx.x * 4 + wave;
    int k0 = __builtin_amdgcn_readfirstlane(rowStart[r]);
    int k1 = __builtin_amdgcn_readfirstlane(rowStart[r + 1]);

    int c = lane;                   // S cols: c and c+64
    float w0a = W1[c],       w1a = W1[128 + c];
    float w2a = W1[256 + c], w3a = W1[384 + c];
    float w0b = W1[c + 64],  w1b = W1[192 + c];
    float w2b = W1[320 + c], w3b = W1[448 + c];
    float ba = b1[c], bb = b1[c + 64];
    float accA = 0.f, accB = 0.f;

    int b  = lane >> 5;
    int c4 = lane & 31;
    const float* xbase = x + (size_t)b * ((size_t)E_ * 128) + c4 * 4;
    f32x4 aX = {0.f, 0.f, 0.f, 0.f};

    for (int k = k0; k < k1; k += 8) {
        int eid[8];
        #pragma unroll
        for (int u = 0; u < 8; ++u) {
            int idx = k + u;
            idx = (idx < k1) ? idx : (k1 - 1);
            eid[u] = __builtin_amdgcn_readfirstlane(edge_ids[idx]);
        }
        // issue all 8 x dwordx4 loads, keep in flight
        f32x4 xv[8];
        #pragma unroll
        for (int u = 0; u < 8; ++u)
            xv[u] = *(const f32x4*)(xbase + (size_t)eid[u] * 128);
        // MLP on ea (uniform scalar loads) while x loads are in flight
        #pragma unroll
        for (int u = 0; u < 8; ++u) {
            float4 q = *(const float4*)(ea + (size_t)eid[u] * 4);
            float pa = fmaf(q.x, w0a, fmaf(q.y, w1a,
                       fmaf(q.z, w2a, fmaf(q.w, w3a, ba))));
            float pb = fmaf(q.x, w0b, fmaf(q.y, w1b,
                       fmaf(q.z, w2b, fmaf(q.w, w3b, bb))));
            float sa = pa / (1.f + __expf(-pa));
            float sb = pb / (1.f + __expf(-pb));
            bool live = (k + u) < k1;
            accA += live ? sa : 0.f;
            accB += live ? sb : 0.f;
        }
        // consume x loads with tail mask
        #pragma unroll
        for (int u = 0; u < 8; ++u) {
            float m = ((k + u) < k1) ? 1.f : 0.f;
            aX[0] = fmaf(m, xv[u][0], aX[0]);
            aX[1] = fmaf(m, xv[u][1], aX[1]);
            aX[2] = fmaf(m, xv[u][2], aX[2]);
            aX[3] = fmaf(m, xv[u][3], aX[3]);
        }
    }

    // S stores (duplicated per batch), 2B x 64 lanes = coalesced
    unsigned short sa16 = f2bf(accA), sb16 = f2bf(accB);
    size_t base0 = (size_t)r * 256;
    size_t base1 = (size_t)(NREC_ + r) * 256;
    agg_bf[base0 + c] = sa16;
    agg_bf[base0 + c + 64] = sb16;
    agg_bf[base1 + c] = sa16;
    agg_bf[base1 + c + 64] = sb16;
    // x store: 4 bf16 packed = 8B per lane
    unsigned lo = (unsigned)f2bf(aX[0]) | ((unsigned)f2bf(aX[1]) << 16);
    unsigned hi = (unsigned)f2bf(aX[2]) | ((unsigned)f2bf(aX[3]) << 16);
    *(uint2*)(agg_bf + (size_t)(b * NREC_ + r) * 256 + 128 + c4 * 4) =
        make_uint2(lo, hi);
}

// ---- output FFN: out = silu(agg @ L1comb + c1 + cnt*v) @ L2 + c2 ----
// bf16 MFMA 16x16x32. Each block: 64 rows (4 waves x 16 rows).
__global__ __launch_bounds__(256) void ffn_kernel(
        const unsigned short* __restrict__ agg,
        const unsigned short* __restrict__ L1T, const float* __restrict__ c1,
        const unsigned short* __restrict__ L2T, const float* __restrict__ c2,
        const float* __restrict__ v, const int* __restrict__ cnt,
        float* __restrict__ out) {
    __shared__ unsigned short T[64][264];
    int tid  = threadIdx.x;
    int wave = tid >> 6;
    int lane = tid & 63;
    int quad = lane >> 4;
    int l16  = lane & 15;
    int m0 = blockIdx.x * 64 + wave * 16;

    float cntv[4];
    #pragma unroll
    for (int rr = 0; rr < 4; ++rr) {
        int m = m0 + quad * 4 + rr;
        int r = (m >= NREC_) ? m - NREC_ : m;
        cntv[rr] = (float)cnt[r];
    }

    short8 afrag[8];
    const unsigned short* aptr = agg + (size_t)(m0 + l16) * 256 + quad * 8;
    #pragma unroll
    for (int ks = 0; ks < 8; ++ks)
        afrag[ks] = *(const short8*)(aptr + ks * 32);

    #pragma unroll 2
    for (int nt = 0; nt < 16; ++nt) {
        f32x4 acc = {0.f, 0.f, 0.f, 0.f};
        const unsigned short* bptr = L1T + (size_t)(nt * 16 + l16) * 256 + quad * 8;
        #pragma unroll
        for (int ks = 0; ks < 8; ++ks) {
            short8 bfrag = *(const short8*)(bptr + ks * 32);
            acc = __builtin_amdgcn_mfma_f32_16x16x32_bf16(afrag[ks], bfrag, acc, 0, 0, 0);
        }
        #pragma unroll
        for (int rr = 0; rr < 4; ++rr) {
            int row = quad * 4 + rr;
            int col = nt * 16 + l16;
            float pv = acc[rr] + c1[col] + cntv[rr] * v[col];
            pv = pv / (1.f + __expf(-pv));
            T[wave * 16 + row][col] = f2bf(pv);
        }
    }
    __syncthreads();

    short8 afrag2[8];
    #pragma unroll
    for (int ks = 0; ks < 8; ++ks)
        afrag2[ks] = *(const short8*)&T[wave * 16 + l16][ks * 32 + quad * 8];

    #pragma unroll 2
    for (int nt = 0; nt < 16; ++nt) {
        f32x4 acc = {0.f, 0.f, 0.f, 0.f};
        const unsigned short* bptr = L2T + (size_t)(nt * 16 + l16) * 256 + quad * 8;
        #pragma unroll
        for (int ks = 0; ks < 8; ++ks) {
            short8 bfrag = *(const short8*)(bptr + ks * 32);
            acc = __builtin_amdgcn_mfma_f32_16x16x32_bf16(afrag2[ks], bfrag, acc, 0, 0, 0);
        }
        #pragma unroll
        for (int rr = 0; rr < 4; ++rr) {
            int row = m0 + quad * 4 + rr;
            int col = nt * 16 + l16;
            out[(size_t)row * 256 + col] = acc[rr] + c2[col];
        }
    }
}

extern "C" void kernel_launch(void* const* d_in, const int* in_sizes, int n_in,
                              void* d_out, int out_size, void* d_ws, size_t ws_size,
                              hipStream_t stream) {
    const float* x          = (const float*)d_in[0];
    const float* edge_attr  = (const float*)d_in[1];
    const int*   edge_index = (const int*)d_in[2];
    const float* W1 = (const float*)d_in[3];
    const float* b1 = (const float*)d_in[4];
    const float* W2 = (const float*)d_in[5];
    const float* b2 = (const float*)d_in[6];
    const float* L1 = (const float*)d_in[7];
    const float* c1 = (const float*)d_in[8];
    const float* L2 = (const float*)d_in[9];
    const float* c2 = (const float*)d_in[10];
    float* out = (float*)d_out;

    // workspace layout (16B aligned)
    int* cnt      = (int*)d_ws;                 // 12288
    int* rowStart = cnt + NREC_;                // 12289 (pad to 12292)
    int* cursor   = rowStart + NREC_ + 4;       // 12288
    int* edge_ids = cursor + NREC_;             // 196608
    unsigned short* agg_bf = (unsigned short*)(edge_ids + E_);   // M_*256
    unsigned short* L1T = agg_bf + (size_t)M_ * 256;             // 65536
    unsigned short* L2T = L1T + 256 * 256;                       // 65536
    float* v = (float*)(L2T + 256 * 256);                        // 256

    const int* recv = edge_index + E_;   // edge_index[1]

    hipMemsetAsync(cnt, 0, NREC_ * sizeof(int), stream);
    precompute<<<512, 256, 0, stream>>>(W2, b2, L1, L2, L1T, L2T, v);
    count_kernel<<<(E_ + 255) / 256, 256, 0, stream>>>(recv, cnt);
    scan_kernel<<<1, 1024, 0, stream>>>(cnt, rowStart, cursor);
    fill_kernel<<<(E_ + 255) / 256, 256, 0, stream>>>(recv, cursor, edge_ids);
    gather_kernel<<<NREC_ / 4, 256, 0, stream>>>(x, edge_attr, W1, b1,
                                                 rowStart, edge_ids, agg_bf);
    ffn_kernel<<<M_ / 64, 256, 0, stream>>>(agg_bf, L1T, c1, L2T, c2, v, cnt, out);
}